// Round 7
// baseline (29.006 us; speedup 1.0000x reference)
//
#include <hip/hip_runtime.h>
#include <math.h>

// MaxYager2d: out[b,f,si,sj] = max(0, 1 - (min_{c,kh,kw} A[b,c,si+kh,sj+kw] + BW[c,kh,kw,f])^(2/3))
// where A = (1-x)^1.5, BW = (1-w)^1.5.  Max over J commutes with the
// monotone-decreasing Yager combine -> tropical min-plus 3x3 conv.
//
// r7: two dispatches (r5 structure). minconv reworked:
//  - fpt=4 (each wave: 64 cols x 4 f) -> per-CU LDS A-read traffic halves
//  - A tile cp-major: [kr][col][16 half2] = 64B/(kr,col); ds_read_b128 gets
//    4 channel-pairs per tap; cp-block slot XOR-swizzled by col so lanes
//    spread across banks (2-way = free); read applies same XOR (bits [4:5]).
//  - bw pre-transposed [f][q][t][jj] -> wave-uniform s_load_dwordx4 operands
//  - grid 512 (2 blocks/CU): one block computes while the other stages.

#define CIN  32
#define CP   16   // channel pairs
#define FOUT 32
#define KS   3
#define HW   66   // input spatial
#define SS   64   // output spatial
#define NB   4    // batch
#define JDIM (CIN * KS * KS)

typedef _Float16 half2_t __attribute__((ext_vector_type(2)));
typedef _Float16 half8_t __attribute__((ext_vector_type(8)));   // 4 half2 = 16B

static __device__ __forceinline__ half2_t mk2(float a, float b) {
    half2_t r; r.x = (_Float16)a; r.y = (_Float16)b; return r;
}
static __device__ __forceinline__ half8_t splat8(float v) {
    _Float16 h = (_Float16)v;
    half8_t r = {h, h, h, h, h, h, h, h};
    return r;
}

// bwq[((f*4+q)*9+t)] is a half8: jj=0..3 -> channel pair cp=4q+jj
__global__ __launch_bounds__(256) void yager_prep_bw(
    const float* __restrict__ w, half2_t* __restrict__ bwp)
{
    int i = blockIdx.x * 256 + threadIdx.x;     // over [f][q][t][jj], 32*4*9*4=4608
    if (i >= FOUT * 4 * 9 * 4) return;
    int jj = i & 3;
    int r  = i >> 2;
    int t  = r % 9;
    int r2 = r / 9;
    int q  = r2 & 3;
    int f  = r2 >> 2;
    int c0 = 8 * q + 2 * jj;
    float w0 = w[(c0 * 9 + t) * FOUT + f];
    float w1 = w[((c0 + 1) * 9 + t) * FOUT + f];
    float t0 = 1.0f - w0, t1 = 1.0f - w1;
    bwp[i] = mk2(t0 * sqrtf(t0), t1 * sqrtf(t1));   // (1-w)^1.5
}

__global__ __launch_bounds__(256, 2) void yager_minconv(
    const float* __restrict__ x, const half8_t* __restrict__ bwq,
    float* __restrict__ out)
{
    // [kr][col][4 cp-blocks of half8]; slot swizzled by g(col)=(col&3)^((col>>2)&3)
    __shared__ half8_t ldsA[KS * HW * 4];   // 12.4 KB

    const int tid   = threadIdx.x;
    const int fhalf = blockIdx.x & 1;           // f in [fhalf*16, fhalf*16+16)
    const int rowb  = blockIdx.x >> 1;
    const int row   = rowb & (SS - 1);
    const int b     = rowb >> 6;

    // --- stage A window (3 rows x 32 ch as 16 half2), A = t*sqrt(t)
    for (int i = tid; i < CP * KS * HW; i += 256) {
        int cp  = i / (KS * HW);
        int r   = i - cp * (KS * HW);
        int kr  = r / HW;
        int col = r - kr * HW;
        const float* xp = x + ((size_t)(b * CIN + 2 * cp) * HW + row + kr) * HW + col;
        float t0 = 1.0f - xp[0];
        float t1 = 1.0f - xp[HW * HW];
        int g   = ((col & 3) ^ ((col >> 2) & 3));
        int blk = ((cp >> 2) ^ g) & 3;
        ((half2_t*)&ldsA[(kr * HW + col) * 4 + blk])[cp & 3] = mk2(t0 * sqrtf(t0), t1 * sqrtf(t1));
    }
    __syncthreads();

    const int lane = tid & 63;                                        // output col
    const int fb   = __builtin_amdgcn_readfirstlane(fhalf * 16 + (tid >> 6) * 4);

    // per-kw column swizzle terms (lane-dependent)
    int sw[KS], cb[KS];
#pragma unroll
    for (int kw = 0; kw < KS; ++kw) {
        int c  = lane + kw;
        sw[kw] = ((c & 3) ^ ((c >> 2) & 3));
        cb[kw] = c * 4;                          // half8 index of col c, kr=0, slot 0
    }

    half8_t M[4];
#pragma unroll
    for (int f = 0; f < 4; ++f) M[f] = splat8(4.0f);   // > max possible (a+b <= 2)

#pragma unroll 2
    for (int q = 0; q < 4; ++q) {
        half8_t a[KS][KS];
#pragma unroll
        for (int kr = 0; kr < KS; ++kr)
#pragma unroll
            for (int kw = 0; kw < KS; ++kw)
                a[kr][kw] = ldsA[kr * (HW * 4) + cb[kw] + (q ^ sw[kw])];
#pragma unroll
        for (int f = 0; f < 4; ++f) {
            const half8_t* __restrict__ bwf = bwq + ((size_t)(fb + f) * 4 + q) * 9;
#pragma unroll
            for (int t = 0; t < 9; ++t) {
                half8_t s = a[t / 3][t % 3] + bwf[t];   // 4x v_pk_add_f16 (sgpr src)
                M[f] = __builtin_elementwise_min(M[f], s);
            }
        }
    }

#pragma unroll
    for (int f = 0; f < 4; ++f) {
        float m = (float)M[f][0];
#pragma unroll
        for (int k = 1; k < 8; ++k) m = fminf(m, (float)M[f][k]);
        float r = 1.0f - exp2f(0.6666666667f * log2f(m));
        out[(((size_t)b * FOUT + fb + f) * SS + row) * SS + lane] = fmaxf(r, 0.0f);
    }
}

// Fallback if workspace is too small for bwq: fused f32 kernel (r1-proven).
__global__ __launch_bounds__(256) void yager_fused(
    const float* __restrict__ x, const float* __restrict__ w,
    float* __restrict__ out)
{
    __shared__ float bws[JDIM * FOUT];   // 36 KB
    for (int i = threadIdx.y * 64 + threadIdx.x; i < JDIM * FOUT; i += 256) {
        float t = 1.0f - w[i];
        bws[i] = t * sqrtf(t);
    }
    __syncthreads();

    const int col = threadIdx.x;
    const int fg  = threadIdx.y;
    const int row = blockIdx.x & (SS - 1);
    const int b   = blockIdx.x >> 6;

    const float* xb = x + ((size_t)(b * CIN) * HW + row) * HW + col;
    float m[8];
#pragma unroll
    for (int f = 0; f < 8; ++f) m[f] = 3.0f;

    for (int c = 0; c < CIN; ++c) {
        const float* xc = xb + (size_t)c * HW * HW;
        const float* bc = bws + c * (KS * KS) * FOUT + fg * 8;
#pragma unroll
        for (int kh = 0; kh < KS; ++kh)
#pragma unroll
            for (int kw = 0; kw < KS; ++kw) {
                float t = 1.0f - xc[kh * HW + kw];
                const float a = t * sqrtf(t);
                const float* br = bc + (kh * KS + kw) * FOUT;
#pragma unroll
                for (int f = 0; f < 8; ++f)
                    m[f] = fminf(m[f], a + br[f]);
            }
    }

    float* op = out + (((size_t)b * FOUT + fg * 8) * SS + row) * SS + col;
#pragma unroll
    for (int f = 0; f < 8; ++f) {
        float r = 1.0f - exp2f(0.6666666667f * log2f(m[f]));
        op[(size_t)f * SS * SS] = fmaxf(r, 0.0f);
    }
}

extern "C" void kernel_launch(void* const* d_in, const int* in_sizes, int n_in,
                              void* d_out, int out_size, void* d_ws, size_t ws_size,
                              hipStream_t stream)
{
    const float* x = (const float*)d_in[0];   // [4,32,66,66] f32
    const float* w = (const float*)d_in[1];   // [288,32] f32
    float* out = (float*)d_out;               // [4,32,64,64] f32

    const int nBW = FOUT * 4 * 9 * 4;         // 4608 half2
    const size_t need = (size_t)nBW * sizeof(half2_t);

    if (ws_size >= need) {
        half2_t* bwp = (half2_t*)d_ws;
        yager_prep_bw<<<(nBW + 255) / 256, 256, 0, stream>>>(w, bwp);
        yager_minconv<<<NB * SS * 2, 256, 0, stream>>>(x, (const half8_t*)bwp, out);
    } else {
        dim3 blk(64, 4);
        dim3 grd(NB * SS);
        yager_fused<<<grd, blk, 0, stream>>>(x, w, out);
    }
}

// Round 8
// 23.913 us; speedup vs baseline: 1.2130x; 1.2130x over previous
//
#include <hip/hip_runtime.h>
#include <math.h>

// MaxYager2d: out[b,f,si,sj] = max(0, 1 - (min_{c,kh,kw} A[b,c,si+kh,sj+kw] + BW[c,kh,kw,f])^(2/3))
// where A = (1-x)^1.5, BW = (1-w)^1.5.  Max over J commutes with the
// monotone-decreasing Yager combine -> tropical min-plus 3x3 conv.
//
// r8: r5 skeleton, two changes targeting the serial-latency term:
//  1) b-operands via VGPR+readlane instead of s_load: each wave loads its
//     288-dword b-slab once (coalesced) into 5 VGPRs; fully-unrolled inner
//     loop uses __builtin_amdgcn_readlane with compile-time lanes. No SMEM
//     in the loop -> lgkmcnt is pure in-order ds_read -> LDS pipelines.
//  2) 4x 256-thread blocks per (b,row) instead of one 1024-thread block:
//     same 16 waves/CU, but 4 independent phase-diverse blocks (stage of one
//     overlaps compute of others; 4-wave barriers).

#define CIN  32
#define CP   16   // channel pairs
#define FOUT 32
#define KS   3
#define HW   66   // input spatial
#define SS   64   // output spatial
#define NB   4    // batch
#define JDIM (CIN * KS * KS)   // 288
#define LDW  68   // padded LDS row width

typedef _Float16 half2_t __attribute__((ext_vector_type(2)));

static __device__ __forceinline__ half2_t mk2(float a, float b) {
    half2_t r; r.x = (_Float16)a; r.y = (_Float16)b; return r;
}
static __device__ __forceinline__ half2_t bcast(int v) {
    union { int i; half2_t h; } u; u.i = v; return u.h;
}

// bwT[f][cp][t] = half2( (1-w[(2cp*9+t)*32+f])^1.5 , (1-w[((2cp+1)*9+t)*32+f])^1.5 )
__global__ __launch_bounds__(256) void yager_prep_bw(
    const float* __restrict__ w, half2_t* __restrict__ bwp)
{
    int i = blockIdx.x * 256 + threadIdx.x;     // over [f][cp][t], 32*16*9 = 4608
    if (i >= FOUT * CP * 9) return;
    int f  = i / (CP * 9);
    int r  = i - f * (CP * 9);
    int cp = r / 9;
    int t  = r - cp * 9;
    float w0 = w[((2 * cp)     * 9 + t) * FOUT + f];
    float w1 = w[((2 * cp + 1) * 9 + t) * FOUT + f];
    float t0 = 1.0f - w0, t1 = 1.0f - w1;
    bwp[i] = mk2(t0 * sqrtf(t0), t1 * sqrtf(t1));   // t^1.5
}

__global__ __launch_bounds__(256, 4) void yager_minconv(
    const float* __restrict__ x, const int* __restrict__ bwT,
    float* __restrict__ out)
{
    __shared__ half2_t ldsA[CP][KS][LDW];   // 13 KB

    const int tid  = threadIdx.x;
    const int fq   = blockIdx.x & 3;            // f-quartet (8 f)
    const int rowb = blockIdx.x >> 2;
    const int row  = rowb & (SS - 1);
    const int b    = rowb >> 6;
    const int lane = tid & 63;
    const int wv   = tid >> 6;                  // wave 0..3
    const int f0   = fq * 8 + wv * 2;           // this wave's first f

    // Load this wave's b-slab (2 f-rows = 288 dwords) coalesced into VGPRs.
    // b[4] over-reads 32 dwords into the next slab / ws tail — harmless.
    const int* slab = bwT + f0 * (CP * 9);
    int bv[5];
#pragma unroll
    for (int k = 0; k < 5; ++k) bv[k] = slab[lane + 64 * k];

    // Stage A window (3 rows x 32 ch as 16 half2), fusing A = t*sqrt(t).
    for (int i = tid; i < CP * KS * HW; i += 256) {
        int cp  = i / (KS * HW);
        int r   = i - cp * (KS * HW);
        int kr  = r / HW;
        int col = r - kr * HW;
        const float* xp = x + ((size_t)(b * CIN + 2 * cp) * HW + row + kr) * HW + col;
        float t0 = 1.0f - xp[0];
        float t1 = 1.0f - xp[HW * HW];
        ldsA[cp][kr][col] = mk2(t0 * sqrtf(t0), t1 * sqrtf(t1));
    }
    __syncthreads();

    half2_t M0 = mk2(4.0f, 4.0f);   // > max possible sum (a+b <= 2)
    half2_t M1 = M0;

#pragma unroll
    for (int cp = 0; cp < CP; ++cp) {
        half2_t a[KS][KS];
#pragma unroll
        for (int kr = 0; kr < KS; ++kr)
#pragma unroll
            for (int kw = 0; kw < KS; ++kw)
                a[kr][kw] = ldsA[cp][kr][lane + kw];
#pragma unroll
        for (int t = 0; t < 9; ++t) {
            const int e0 = cp * 9 + t;              // compile-time
            const int e1 = CP * 9 + e0;
            half2_t b0 = bcast(__builtin_amdgcn_readlane(bv[e0 >> 6], e0 & 63));
            half2_t b1 = bcast(__builtin_amdgcn_readlane(bv[e1 >> 6], e1 & 63));
            half2_t av = a[t / 3][t % 3];
            M0 = __builtin_elementwise_min(M0, (half2_t)(av + b0));
            M1 = __builtin_elementwise_min(M1, (half2_t)(av + b1));
        }
    }

    float m0 = fminf((float)M0.x, (float)M0.y);
    float m1 = fminf((float)M1.x, (float)M1.y);
    float r0 = 1.0f - exp2f(0.6666666667f * log2f(m0));
    float r1 = 1.0f - exp2f(0.6666666667f * log2f(m1));
    float* op = out + (((size_t)b * FOUT + f0) * SS + row) * SS + lane;
    op[0]       = fmaxf(r0, 0.0f);
    op[SS * SS] = fmaxf(r1, 0.0f);
}

// Fallback if workspace is too small for bwT: fused f32 kernel (r1-proven).
__global__ __launch_bounds__(256) void yager_fused(
    const float* __restrict__ x, const float* __restrict__ w,
    float* __restrict__ out)
{
    __shared__ float bws[JDIM * FOUT];   // 36 KB
    for (int i = threadIdx.y * 64 + threadIdx.x; i < JDIM * FOUT; i += 256) {
        float t = 1.0f - w[i];
        bws[i] = t * sqrtf(t);
    }
    __syncthreads();

    const int col = threadIdx.x;
    const int fg  = threadIdx.y;
    const int row = blockIdx.x & (SS - 1);
    const int b   = blockIdx.x >> 6;

    const float* xb = x + ((size_t)(b * CIN) * HW + row) * HW + col;
    float m[8];
#pragma unroll
    for (int f = 0; f < 8; ++f) m[f] = 3.0f;

    for (int c = 0; c < CIN; ++c) {
        const float* xc = xb + (size_t)c * HW * HW;
        const float* bc = bws + c * (KS * KS) * FOUT + fg * 8;
#pragma unroll
        for (int kh = 0; kh < KS; ++kh)
#pragma unroll
            for (int kw = 0; kw < KS; ++kw) {
                float t = 1.0f - xc[kh * HW + kw];
                const float a = t * sqrtf(t);
                const float* br = bc + (kh * KS + kw) * FOUT;
#pragma unroll
                for (int f = 0; f < 8; ++f)
                    m[f] = fminf(m[f], a + br[f]);
            }
    }

    float* op = out + (((size_t)b * FOUT + fg * 8) * SS + row) * SS + col;
#pragma unroll
    for (int f = 0; f < 8; ++f) {
        float r = 1.0f - exp2f(0.6666666667f * log2f(m[f]));
        op[(size_t)f * SS * SS] = fmaxf(r, 0.0f);
    }
}

extern "C" void kernel_launch(void* const* d_in, const int* in_sizes, int n_in,
                              void* d_out, int out_size, void* d_ws, size_t ws_size,
                              hipStream_t stream)
{
    const float* x = (const float*)d_in[0];   // [4,32,66,66] f32
    const float* w = (const float*)d_in[1];   // [288,32] f32
    float* out = (float*)d_out;               // [4,32,64,64] f32

    const int nBW = FOUT * CP * 9;            // 4608 half2
    // +32 dwords slack for the benign over-read of bv[4] on the last slab
    const size_t need = (size_t)(nBW + 32) * sizeof(half2_t);

    if (ws_size >= need) {
        half2_t* bwp = (half2_t*)d_ws;
        yager_prep_bw<<<(nBW + 255) / 256, 256, 0, stream>>>(w, bwp);
        yager_minconv<<<NB * SS * 4, 256, 0, stream>>>(x, (const int*)bwp, out);
    } else {
        dim3 blk(64, 4);
        dim3 grd(NB * SS);
        yager_fused<<<grd, blk, 0, stream>>>(x, w, out);
    }
}

// Round 9
// 16.298 us; speedup vs baseline: 1.7797x; 1.4672x over previous
//
#include <hip/hip_runtime.h>
#include <math.h>

// MaxYager2d: out[b,f,si,sj] = max(0, 1 - (min_{c,kh,kw} A[b,c,si+kh,sj+kw] + BW[c,kh,kw,f])^(2/3))
// where A = (1-x)^1.5, BW = (1-w)^1.5.  Max over J commutes with the
// monotone-decreasing Yager combine -> tropical min-plus 3x3 conv.
//
// r9: ONE dispatch. Per block (1024 thr, one (b,row), grid 256 = 1/CU):
//  - B staged to LDS from w with fully-coalesced loads (9216 dw = 9/thread)
//    + b16 transpose-scatter; layout [f][t][16 cp-half2] so the compute loop
//    reads B as wave-uniform broadcast ds_read_b128 (4 ch-pairs/instr).
//  - A staged as r5: [cp][kr][68] half2, fused (1-x)^1.5.
//  - NO s_load in the loop -> lgkmcnt is a pure in-order ds stream -> compiler
//    emits counted waits, no per-iteration pipeline flushes; no prep kernel,
//    no graph dependency, no workspace.
// Arithmetic identical to r5 (absmax 0.00390625 expected unchanged).

#define CIN  32
#define CP   16   // channel pairs
#define FOUT 32
#define KS   3
#define HW   66   // input spatial
#define SS   64   // output spatial
#define NB   4    // batch

typedef _Float16 half2_t __attribute__((ext_vector_type(2)));
typedef _Float16 half8_t __attribute__((ext_vector_type(8)));   // 4 half2 = 16B

static __device__ __forceinline__ half2_t mk2(float a, float b) {
    half2_t r; r.x = (_Float16)a; r.y = (_Float16)b; return r;
}

union bvec {
    half8_t v8;
    half2_t v2[4];
};

__global__ __launch_bounds__(1024) void yager_one(
    const float* __restrict__ x, const float* __restrict__ w,
    float* __restrict__ out)
{
    __shared__ half2_t ldsA[CP][KS][68];        // 13.1 KB  [cp][kr][col]
    __shared__ _Float16 ldsB[FOUT][9][CIN];     // 18.4 KB  [f][t][c] (16 half2/row)

    const int tid = threadIdx.x;
    const int row = blockIdx.x & (SS - 1);
    const int b   = blockIdx.x >> 6;

    // --- stage B: coalesced w reads (exactly 9 per thread), transpose scatter.
    // w[i]: f = i&31, j = i>>5, c = j/9, t = j%9;  B = (1-w)^1.5 as f16.
#pragma unroll
    for (int k = 0; k < 9; ++k) {
        int i  = tid + k * 1024;
        float v = w[i];
        int f  = i & 31;
        int j  = i >> 5;
        int c  = j / 9;
        int t  = j - 9 * c;
        float tt = 1.0f - v;
        ldsB[f][t][c] = (_Float16)(tt * sqrtf(tt));
    }

    // --- stage A window (3 rows x 32 ch as 16 half2), fusing A = t*sqrt(t).
    for (int i = tid; i < CP * KS * HW; i += 1024) {
        int cp  = i / (KS * HW);
        int r   = i - cp * (KS * HW);
        int kr  = r / HW;
        int col = r - kr * HW;
        const float* xp = x + ((size_t)(b * CIN + 2 * cp) * HW + row + kr) * HW + col;
        float t0 = 1.0f - xp[0];
        float t1 = 1.0f - xp[HW * HW];
        ldsA[cp][kr][col] = mk2(t0 * sqrtf(t0), t1 * sqrtf(t1));
    }
    __syncthreads();

    const int lane = tid & 63;          // output col
    const int wv   = tid >> 6;          // wave 0..15
    const int f0   = wv * 2;            // this wave's f pair

    half2_t M0 = mk2(4.0f, 4.0f);       // > max possible sum (a+b <= 2)
    half2_t M1 = M0;

#pragma unroll
    for (int q = 0; q < 4; ++q) {       // cp groups of 4
        // B for this group: wave-uniform broadcast b128 (4 ch-pairs each)
        bvec bq0[9], bq1[9];
#pragma unroll
        for (int t = 0; t < 9; ++t) {
            bq0[t].v8 = *(const half8_t*)&ldsB[f0][t][8 * q];
            bq1[t].v8 = *(const half8_t*)&ldsB[f0 + 1][t][8 * q];
        }
#pragma unroll
        for (int i = 0; i < 4; ++i) {
            const int cp = 4 * q + i;
            half2_t a[KS][KS];
#pragma unroll
            for (int kr = 0; kr < KS; ++kr)
#pragma unroll
                for (int kw = 0; kw < KS; ++kw)
                    a[kr][kw] = ldsA[cp][kr][lane + kw];
#pragma unroll
            for (int t = 0; t < 9; ++t) {
                half2_t av = a[t / 3][t % 3];
                M0 = __builtin_elementwise_min(M0, (half2_t)(av + bq0[t].v2[i]));
                M1 = __builtin_elementwise_min(M1, (half2_t)(av + bq1[t].v2[i]));
            }
        }
    }

    float m0 = fminf((float)M0.x, (float)M0.y);
    float m1 = fminf((float)M1.x, (float)M1.y);
    float r0 = 1.0f - exp2f(0.6666666667f * log2f(m0));
    float r1 = 1.0f - exp2f(0.6666666667f * log2f(m1));
    float* op = out + (((size_t)b * FOUT + f0) * SS + row) * SS + lane;
    op[0]       = fmaxf(r0, 0.0f);
    op[SS * SS] = fmaxf(r1, 0.0f);
}

extern "C" void kernel_launch(void* const* d_in, const int* in_sizes, int n_in,
                              void* d_out, int out_size, void* d_ws, size_t ws_size,
                              hipStream_t stream)
{
    const float* x = (const float*)d_in[0];   // [4,32,66,66] f32
    const float* w = (const float*)d_in[1];   // [288,32] f32
    float* out = (float*)d_out;               // [4,32,64,64] f32
    (void)d_ws; (void)ws_size;

    yager_one<<<NB * SS, 1024, 0, stream>>>(x, w, out);
}